// Round 3
// baseline (647.683 us; speedup 1.0000x reference)
//
#include <hip/hip_runtime.h>

// Sparse Adam: out = stack([new_param, new_exp_avg, new_exp_avg_sq]) : [3, N, D] f32
// N = 1e6, M = 2.5e5, D = 32. Memory-bound: ~805 MB fused traffic -> ~128us floor.

#define ADAM_EPS 1e-15f

// Scatter the inverse index map: inv[index[m]] = m. inv pre-filled with -1 (0xFF memset).
__global__ __launch_bounds__(256) void scatter_inv_k(const int* __restrict__ idx,
                                                     int* __restrict__ inv, int M) {
    int m = blockIdx.x * 256 + threadIdx.x;
    if (m < M) inv[idx[m]] = m;
}

// One pass over all N rows (as float4 = 8 vecs/row). Copies untouched rows,
// applies Adam update to visible rows. Writes all three output planes.
__global__ __launch_bounds__(256) void fused_adam_k(
    const float4* __restrict__ param, const float4* __restrict__ grad,
    const float4* __restrict__ ea, const float4* __restrict__ eas,
    const int* __restrict__ inv, const int* __restrict__ step_p,
    float4* __restrict__ out, long long nvec /* = N*D/4 */) {
    // Bias corrections: exact integer pow in double (matches python B**step), ~10 iters.
    int step = *step_p;
    double b1p = 1.0, b2p = 1.0, b1 = 0.9, b2 = 0.999;
    int e = step;
    while (e) { if (e & 1) { b1p *= b1; b2p *= b2; } b1 *= b1; b2 *= b2; e >>= 1; }
    const float isb2 = 1.0f / sqrtf((float)(1.0 - b2p));          // 1/sqrt(bc2)
    const float lrbc = (float)(1.6e-4 / (1.0 - b1p));             // LR/bc1

    const long long stride = (long long)gridDim.x * blockDim.x;
    for (long long t = blockIdx.x * (long long)blockDim.x + threadIdx.x;
         t < nvec; t += stride) {
        float4 p = param[t];
        float4 a = ea[t];
        float4 s = eas[t];
        int n = (int)(t >> 3);           // row (D=32 -> 8 float4 per row)
        int m = inv[n];
        if (m >= 0) {
            float4 g = grad[(long long)m * 8 + (t & 7)];
            float* pp = (float*)&p; float* aa = (float*)&a;
            float* ss = (float*)&s; float* gg = (float*)&g;
#pragma unroll
            for (int j = 0; j < 4; ++j) {
                float av = aa[j] * 0.9f   + 0.1f   * gg[j];
                float sv = ss[j] * 0.999f + 0.001f * gg[j] * gg[j];
                float dn = sqrtf(sv) * isb2 + ADAM_EPS;
                pp[j] = pp[j] - lrbc * (av / dn);
                aa[j] = av;
                ss[j] = sv;
            }
        }
        out[t]            = p;
        out[nvec + t]     = a;
        out[2 * nvec + t] = s;
    }
}

// ---------- fallback path (ws too small): full copy + scatter update ----------
__global__ __launch_bounds__(256) void copy3_k(
    const float4* __restrict__ a, const float4* __restrict__ b,
    const float4* __restrict__ c, float4* __restrict__ out, long long nvec) {
    const long long stride = (long long)gridDim.x * blockDim.x;
    for (long long t = blockIdx.x * (long long)blockDim.x + threadIdx.x;
         t < 3 * nvec; t += stride) {
        float4 v;
        if (t < nvec)            v = a[t];
        else if (t < 2 * nvec)   v = b[t - nvec];
        else                     v = c[t - 2 * nvec];
        out[t] = v;
    }
}

__global__ __launch_bounds__(256) void scatter_update_k(
    const float4* __restrict__ param, const float4* __restrict__ grad,
    const float4* __restrict__ ea, const float4* __restrict__ eas,
    const int* __restrict__ idx, const int* __restrict__ step_p,
    float4* __restrict__ out, long long nvec, int M) {
    int step = *step_p;
    double b1p = 1.0, b2p = 1.0, b1 = 0.9, b2 = 0.999;
    int e = step;
    while (e) { if (e & 1) { b1p *= b1; b2p *= b2; } b1 *= b1; b2 *= b2; e >>= 1; }
    const float isb2 = 1.0f / sqrtf((float)(1.0 - b2p));
    const float lrbc = (float)(1.6e-4 / (1.0 - b1p));

    long long total = (long long)M * 8;
    const long long stride = (long long)gridDim.x * blockDim.x;
    for (long long t = blockIdx.x * (long long)blockDim.x + threadIdx.x;
         t < total; t += stride) {
        int m = (int)(t >> 3);
        int q = (int)(t & 7);
        int i = idx[m];
        long long o = (long long)i * 8 + q;
        float4 p = param[o];
        float4 a = ea[o];
        float4 s = eas[o];
        float4 g = grad[t];
        float* pp = (float*)&p; float* aa = (float*)&a;
        float* ss = (float*)&s; float* gg = (float*)&g;
#pragma unroll
        for (int j = 0; j < 4; ++j) {
            float av = aa[j] * 0.9f   + 0.1f   * gg[j];
            float sv = ss[j] * 0.999f + 0.001f * gg[j] * gg[j];
            float dn = sqrtf(sv) * isb2 + ADAM_EPS;
            pp[j] = pp[j] - lrbc * (av / dn);
            aa[j] = av;
            ss[j] = sv;
        }
        out[o]            = p;
        out[nvec + o]     = a;
        out[2 * nvec + o] = s;
    }
}

extern "C" void kernel_launch(void* const* d_in, const int* in_sizes, int n_in,
                              void* d_out, int out_size, void* d_ws, size_t ws_size,
                              hipStream_t stream) {
    const float4* param = (const float4*)d_in[0];
    const float4* grad  = (const float4*)d_in[1];
    const float4* ea    = (const float4*)d_in[2];
    const float4* eas   = (const float4*)d_in[3];
    const int*    idx   = (const int*)d_in[4];
    const int*    stepp = (const int*)d_in[5];

    const long long Nd   = in_sizes[0];       // N*D
    const int       M    = in_sizes[4];
    const int       N    = (int)(Nd / 32);
    const long long nvec = Nd / 4;            // float4 per plane
    float4* out = (float4*)d_out;

    if (ws_size >= (size_t)N * sizeof(int)) {
        int* inv = (int*)d_ws;
        hipMemsetAsync(inv, 0xFF, (size_t)N * sizeof(int), stream);   // inv[n] = -1
        scatter_inv_k<<<(M + 255) / 256, 256, 0, stream>>>(idx, inv, M);
        fused_adam_k<<<2048, 256, 0, stream>>>(param, grad, ea, eas, inv, stepp,
                                               out, nvec);
    } else {
        copy3_k<<<2048, 256, 0, stream>>>(param, ea, eas, out, nvec);
        scatter_update_k<<<2048, 256, 0, stream>>>(param, grad, ea, eas, idx, stepp,
                                                   out, nvec, M);
    }
}